// Round 5
// baseline (545.493 us; speedup 1.0000x reference)
//
#include <hip/hip_runtime.h>
#include <hip/hip_bf16.h>
#include <hip/hip_fp16.h>

// RGCN: 3 layers of basis-decomposed relational graph conv + predictor.
// CSR build via 2-level counting sort (NO global atomics).
// Each layer is ONE fused kernel (64-node tile per 256-thread block):
//   phase 1 (gather): quad-per-node fp16 gather (4 rows per wave load instr,
//            2-deep unroll -> 8 rows in flight/wave), fp32 accum in regs,
//            Z written to LDS as swizzled fp16 pairs. comp in VGPRs.
//   phase 2 (GEMM): out = relu([Z | x] @ [bases ; loop_w] + bias) reading
//            A-panels from LDS (2 k per b32 broadcast read), W staged in LDS.
//   Activations live ONLY as fp16 (xq ping-pong); no Z or fp32 x traffic.
// Final: sigmoid(x @ pred_w + pred_b) from fp16.

#define NB1 196        // ceil(100000/512) coarse buckets
#define NBLK1 256      // L1 partition blocks
#define BUCKET_SHIFT 9 // 512 nodes per bucket

typedef unsigned short ushort_t;

__device__ inline ushort_t f2h(float f) {
  __half h = __float2half_rn(f);
  return *(ushort_t*)&h;
}
__device__ inline float h2f(ushort_t u) {
  __half h = *(__half*)&u;
  return __half2float(h);
}
__device__ inline unsigned int pack2h(float a, float b) {
  return (unsigned int)f2h(a) | ((unsigned int)f2h(b) << 16);
}

// inclusive scan of one int per thread across a 256-thread block
__device__ inline int block_incl_scan_256(int v, int* wsums) {
  int lane = threadIdx.x & 63, wid = threadIdx.x >> 6;
  int s = v;
#pragma unroll
  for (int off = 1; off < 64; off <<= 1) {
    int u = __shfl_up(s, off, 64);
    if (lane >= off) s += u;
  }
  if (lane == 63) wsums[wid] = s;
  __syncthreads();
  if (threadIdx.x == 0) {
    int a = 0;
#pragma unroll
    for (int w = 0; w < 4; ++w) { int t = wsums[w]; wsums[w] = a; a += t; }
  }
  __syncthreads();
  return s + wsums[wid];
}

// ---- L1 pass a: per-block LDS histogram over 196 coarse buckets
__global__ void __launch_bounds__(256) k_l1hist(const int* __restrict__ dst,
                                                int* __restrict__ H, int E, int chunk) {
  __shared__ int h[NB1];
  int t = threadIdx.x;
  if (t < NB1) h[t] = 0;
  __syncthreads();
  int beg = blockIdx.x * chunk;
  int end = min(beg + chunk, E);
  for (int i = beg + t; i < end; i += 256) atomicAdd(&h[dst[i] >> BUCKET_SHIFT], 1);
  __syncthreads();
  if (t < NB1) H[blockIdx.x * NB1 + t] = h[t];
}

// ---- L1 pass b: scan each bucket's column of H -> excl offsets + totals
__global__ void __launch_bounds__(256) k_colscan(int* __restrict__ H,
                                                 int* __restrict__ total) {
  __shared__ int wsums[4];
  int b = blockIdx.x;
  int t = threadIdx.x;
  int v = H[t * NB1 + b];
  int s = block_incl_scan_256(v, wsums);
  H[t * NB1 + b] = s - v;
  if (t == 255) total[b] = s;
}

// ---- L1 pass c: scan bucket totals -> bucket_base
__global__ void __launch_bounds__(256) k_basescan(const int* __restrict__ total,
                                                  int* __restrict__ bucket_base,
                                                  int* __restrict__ row_off, int N) {
  __shared__ int wsums[4];
  int t = threadIdx.x;
  int v = (t < NB1) ? total[t] : 0;
  int s = block_incl_scan_256(v, wsums);
  if (t < NB1) bucket_base[t] = s - v;
  if (t == 255) { bucket_base[NB1] = s; row_off[N] = s; }
}

// ---- L1 pass d: scatter edges into bucket-partitioned epk1 via LDS cursors
__global__ void __launch_bounds__(256) k_scatter1(
    const int* __restrict__ src, const int* __restrict__ dst,
    const int* __restrict__ et, const int* __restrict__ H,
    const int* __restrict__ bucket_base, int* __restrict__ epk1,
    int E, int chunk) {
  __shared__ int cur[NB1];
  int t = threadIdx.x;
  if (t < NB1) cur[t] = bucket_base[t] + H[blockIdx.x * NB1 + t];
  __syncthreads();
  int beg = blockIdx.x * chunk;
  int end = min(beg + chunk, E);
  for (int i = beg + t; i < end; i += 256) {
    int d = dst[i];
    int b = d >> BUCKET_SHIFT;
    int p = atomicAdd(&cur[b], 1);
    epk1[p] = src[i] | (et[i] << 17) | ((d & 511) << 19);
  }
}

// ---- L2: per-bucket exact sort by dst_local (512 bins) -> epk + row_off
__global__ void __launch_bounds__(256) k_bucket(
    const int* __restrict__ epk1, const int* __restrict__ bucket_base,
    int* __restrict__ epk, int* __restrict__ row_off, int N) {
  __shared__ int hist[512];
  __shared__ int cur[512];
  __shared__ int wsums[4];
  int b = blockIdx.x;
  int t = threadIdx.x;
  int ebase = bucket_base[b], eend = bucket_base[b + 1];
  hist[t] = 0; hist[t + 256] = 0;
  __syncthreads();
  for (int i = ebase + t; i < eend; i += 256) atomicAdd(&hist[epk1[i] >> 19], 1);
  __syncthreads();
  int h0 = hist[2 * t], h1 = hist[2 * t + 1];
  int pair = h0 + h1;
  int incl = block_incl_scan_256(pair, wsums);
  int e0 = incl - pair;
  cur[2 * t] = ebase + e0;
  cur[2 * t + 1] = ebase + e0 + h0;
  int n0 = (b << BUCKET_SHIFT) + 2 * t;
  if (n0 < N) row_off[n0] = ebase + e0;
  if (n0 + 1 < N) row_off[n0 + 1] = ebase + e0 + h0;
  __syncthreads();
  for (int i = ebase + t; i < eend; i += 256) {
    int pk = epk1[i];
    int p = atomicAdd(&cur[pk >> 19], 1);
    epk[p] = pk;
  }
}

// ---- quantize fp32 -> fp16 (RTNE), vectorized
__global__ void __launch_bounds__(256) k_quant(const float* __restrict__ in,
                                               ushort_t* __restrict__ out, int n4) {
  int i = blockIdx.x * blockDim.x + threadIdx.x;
  if (i < n4) {
    float4 v = ((const float4*)in)[i];
    ushort4 q;
    q.x = f2h(v.x); q.y = f2h(v.y);
    q.z = f2h(v.z); q.w = f2h(v.w);
    ((ushort4*)out)[i] = q;
  }
}

// ---- fused RGCN layer: 64-node tile per block, 256 threads (4 waves)
__global__ void __launch_bounds__(256) k_layer(
    const ushort_t* __restrict__ xqIn, const int* __restrict__ row_off,
    const int* __restrict__ epk, const float* __restrict__ comp,
    const float* __restrict__ bases, const float* __restrict__ loopw,
    const float* __restrict__ bias, ushort_t* __restrict__ xqOut, int N) {
  __shared__ ushort_t sZ[64 * 128];  // fp16 pairs, XOR-swizzled: 16 KB
  __shared__ ushort_t sX[64 * 64];   // fp16 pairs, XOR-swizzled:  8 KB
  __shared__ float    sW[64 * 64];   // fp32 W chunk:             16 KB
  unsigned int* sZw = (unsigned int*)sZ;
  unsigned int* sXw = (unsigned int*)sX;

  int t = threadIdx.x;
  int w = t >> 6, lane = t & 63;
  int q = lane >> 4, cl = lane & 15;
  int node0 = blockIdx.x * 64;

  // comp[4][2] into registers (wave-uniform)
  float c_[8];
#pragma unroll
  for (int i = 0; i < 8; ++i) c_[i] = comp[i];

  // ---- stage sX (self-loop operand) from xqIn as swizzled pairs
  {
    int r = t >> 2;            // 0..63
    int half = t & 3;          // 16-channel slice
    int grow = node0 + r;
    uint4 v0 = make_uint4(0, 0, 0, 0), v1 = v0;
    if (grow < N) {
      const uint4* p = (const uint4*)(xqIn + (size_t)grow * 64 + half * 16);
      v0 = p[0]; v1 = p[1];
    }
    unsigned int* a = (unsigned int*)&v0;
    unsigned int* b = (unsigned int*)&v1;
    int sw = r & 31;
#pragma unroll
    for (int p2 = 0; p2 < 4; ++p2) {
      sXw[r * 32 + ((half * 8 + p2) ^ sw)]     = a[p2];
      sXw[r * 32 + ((half * 8 + 4 + p2) ^ sw)] = b[p2];
    }
  }

  // ---- gather/aggregate: 4 rounds, quad q owns one node per round.
  // Lane covers channels cl*4..cl*4+3. One wave load instr = 4 rows (512B).
#pragma unroll 1
  for (int g = 0; g < 4; ++g) {
    int r_loc = w * 16 + g * 4 + q;
    int node = node0 + r_loc;
    int beg = 0, end = 0;
    if (node < N) { beg = row_off[node]; end = row_off[node + 1]; }
    float z0[4] = {0.f, 0.f, 0.f, 0.f}, z1[4] = {0.f, 0.f, 0.f, 0.f};
    for (int e = beg; e < end; e += 2) {
      int pk0 = epk[e];
      bool has1 = (e + 1 < end);
      int pk1 = has1 ? epk[e + 1] : pk0;
      int s0 = pk0 & 0x1FFFF, r0 = (pk0 >> 17) & 3;
      int s1 = pk1 & 0x1FFFF, r1 = (pk1 >> 17) & 3;
      ushort4 ga = *(const ushort4*)(xqIn + (size_t)s0 * 64 + cl * 4);
      ushort4 gb = *(const ushort4*)(xqIn + (size_t)s1 * 64 + cl * 4);
      float cA0 = (r0 & 2) ? ((r0 & 1) ? c_[6] : c_[4]) : ((r0 & 1) ? c_[2] : c_[0]);
      float cA1 = (r0 & 2) ? ((r0 & 1) ? c_[7] : c_[5]) : ((r0 & 1) ? c_[3] : c_[1]);
      float xa0 = h2f(ga.x), xa1 = h2f(ga.y), xa2 = h2f(ga.z), xa3 = h2f(ga.w);
      z0[0] = fmaf(cA0, xa0, z0[0]); z1[0] = fmaf(cA1, xa0, z1[0]);
      z0[1] = fmaf(cA0, xa1, z0[1]); z1[1] = fmaf(cA1, xa1, z1[1]);
      z0[2] = fmaf(cA0, xa2, z0[2]); z1[2] = fmaf(cA1, xa2, z1[2]);
      z0[3] = fmaf(cA0, xa3, z0[3]); z1[3] = fmaf(cA1, xa3, z1[3]);
      if (has1) {
        float cB0 = (r1 & 2) ? ((r1 & 1) ? c_[6] : c_[4]) : ((r1 & 1) ? c_[2] : c_[0]);
        float cB1 = (r1 & 2) ? ((r1 & 1) ? c_[7] : c_[5]) : ((r1 & 1) ? c_[3] : c_[1]);
        float xb0 = h2f(gb.x), xb1 = h2f(gb.y), xb2 = h2f(gb.z), xb3 = h2f(gb.w);
        z0[0] = fmaf(cB0, xb0, z0[0]); z1[0] = fmaf(cB1, xb0, z1[0]);
        z0[1] = fmaf(cB0, xb1, z0[1]); z1[1] = fmaf(cB1, xb1, z1[1]);
        z0[2] = fmaf(cB0, xb2, z0[2]); z1[2] = fmaf(cB1, xb2, z1[2]);
        z0[3] = fmaf(cB0, xb3, z0[3]); z1[3] = fmaf(cB1, xb3, z1[3]);
      }
    }
    // write node row to sZ as swizzled fp16 pairs
    int sw = r_loc & 31;
    sZw[r_loc * 64 + ((cl * 2) ^ sw)]          = pack2h(z0[0], z0[1]);
    sZw[r_loc * 64 + ((cl * 2 + 1) ^ sw)]      = pack2h(z0[2], z0[3]);
    sZw[r_loc * 64 + 32 + ((cl * 2) ^ sw)]     = pack2h(z1[0], z1[1]);
    sZw[r_loc * 64 + 32 + ((cl * 2 + 1) ^ sw)] = pack2h(z1[2], z1[3]);
  }
  __syncthreads();

  // ---- GEMM phase: out = relu([Z | x] @ [bases ; loop_w] + bias)
  int tx = t & 15, ty = t >> 4;
  float acc[4][4] = {{0.f, 0.f, 0.f, 0.f}};
#pragma unroll 1
  for (int ch = 0; ch < 3; ++ch) {
    if (ch) __syncthreads();  // protect sW reuse
    const float4* wsrc = (ch < 2) ? ((const float4*)bases + (size_t)ch * 1024)
                                  : (const float4*)loopw;
#pragma unroll
    for (int qq = 0; qq < 4; ++qq) ((float4*)sW)[t + qq * 256] = wsrc[t + qq * 256];
    __syncthreads();
#pragma unroll 2
    for (int m = 0; m < 32; ++m) {
      float4 w0 = *(const float4*)(sW + (2 * m) * 64 + tx * 4);
      float4 w1 = *(const float4*)(sW + (2 * m + 1) * 64 + tx * 4);
#pragma unroll
      for (int j = 0; j < 4; ++j) {
        int rj = ty * 4 + j, sw = rj & 31;
        unsigned int pr;
        if (ch == 0)      pr = sZw[rj * 64 + (m ^ sw)];
        else if (ch == 1) pr = sZw[rj * 64 + 32 + (m ^ sw)];
        else              pr = sXw[rj * 32 + (m ^ sw)];
        float a0 = h2f((ushort_t)(pr & 0xffff));
        float a1 = h2f((ushort_t)(pr >> 16));
        acc[j][0] = fmaf(a0, w0.x, acc[j][0]);
        acc[j][1] = fmaf(a0, w0.y, acc[j][1]);
        acc[j][2] = fmaf(a0, w0.z, acc[j][2]);
        acc[j][3] = fmaf(a0, w0.w, acc[j][3]);
        acc[j][0] = fmaf(a1, w1.x, acc[j][0]);
        acc[j][1] = fmaf(a1, w1.y, acc[j][1]);
        acc[j][2] = fmaf(a1, w1.z, acc[j][2]);
        acc[j][3] = fmaf(a1, w1.w, acc[j][3]);
      }
    }
  }
  // ---- epilogue: bias + relu -> fp16 activations only
  float4 bv = *(const float4*)(bias + tx * 4);
#pragma unroll
  for (int j = 0; j < 4; ++j) {
    int r = node0 + ty * 4 + j;
    if (r < N) {
      float o0 = fmaxf(acc[j][0] + bv.x, 0.f);
      float o1 = fmaxf(acc[j][1] + bv.y, 0.f);
      float o2 = fmaxf(acc[j][2] + bv.z, 0.f);
      float o3 = fmaxf(acc[j][3] + bv.w, 0.f);
      ushort4 qv;
      qv.x = f2h(o0); qv.y = f2h(o1); qv.z = f2h(o2); qv.w = f2h(o3);
      *(ushort4*)(xqOut + (size_t)r * 64 + tx * 4) = qv;
    }
  }
}

__global__ void __launch_bounds__(256) k_pred(
    const ushort_t* __restrict__ x, const float* __restrict__ pw,
    const float* __restrict__ pb, float* __restrict__ out, int N) {
  int node = blockIdx.x * 4 + (threadIdx.x >> 6);
  int lane = threadIdx.x & 63;
  if (node >= N) return;
  float v = h2f(x[(size_t)node * 64 + lane]) * pw[lane];
#pragma unroll
  for (int off = 32; off > 0; off >>= 1) v += __shfl_down(v, off, 64);
  if (lane == 0) {
    float logit = v + pb[0];
    out[node] = 1.f / (1.f + expf(-logit));
  }
}

extern "C" void kernel_launch(void* const* d_in, const int* in_sizes, int n_in,
                              void* d_out, int out_size, void* d_ws, size_t ws_size,
                              hipStream_t stream) {
  const float* features = (const float*)d_in[0];
  const int* src = (const int*)d_in[1];
  const int* dst = (const int*)d_in[2];
  const int* et  = (const int*)d_in[3];
  const float* bases[3] = {(const float*)d_in[4], (const float*)d_in[8],  (const float*)d_in[12]};
  const float* comp[3]  = {(const float*)d_in[5], (const float*)d_in[9],  (const float*)d_in[13]};
  const float* loopw[3] = {(const float*)d_in[6], (const float*)d_in[10], (const float*)d_in[14]};
  const float* biasp[3] = {(const float*)d_in[7], (const float*)d_in[11], (const float*)d_in[15]};
  const float* pred_w = (const float*)d_in[16];
  const float* pred_b = (const float*)d_in[17];

  const int N = in_sizes[0] / 64;   // 100000
  const int E = in_sizes[1];        // 1600000

  char* ws = (char*)d_ws;
  size_t off = 0;
  auto take = [&](size_t bytes) {
    char* p = ws + off;
    off += (bytes + 255) & ~(size_t)255;
    return p;
  };
  int*      row_off     = (int*)     take((size_t)(N + 1) * 4);
  int*      H           = (int*)     take((size_t)NBLK1 * NB1 * 4);
  int*      total       = (int*)     take((size_t)NB1 * 4);
  int*      bucket_base = (int*)     take((size_t)(NB1 + 1) * 4);
  int*      epk         = (int*)     take((size_t)(E + 8) * 4);  // +pad for epk[e+1]
  int*      epk1        = (int*)     take((size_t)E * 4);
  ushort_t* xqA         = (ushort_t*)take((size_t)N * 64 * 2);
  ushort_t* xqB         = (ushort_t*)take((size_t)N * 64 * 2);
  (void)ws_size;

  // ---- CSR build: 2-level counting sort, no global atomics
  int chunk = (E + NBLK1 - 1) / NBLK1;
  k_l1hist  <<<NBLK1, 256, 0, stream>>>(dst, H, E, chunk);
  k_colscan <<<NB1,   256, 0, stream>>>(H, total);
  k_basescan<<<1,     256, 0, stream>>>(total, bucket_base, row_off, N);
  k_scatter1<<<NBLK1, 256, 0, stream>>>(src, dst, et, H, bucket_base, epk1, E, chunk);
  k_bucket  <<<NB1,   256, 0, stream>>>(epk1, bucket_base, epk, row_off, N);

  // ---- quantize input features to fp16
  k_quant<<<(N * 16 + 255) / 256, 256, 0, stream>>>(features, xqA, N * 16);

  // ---- 3 fused RGCN layers (fp16 activations ping-pong)
  ushort_t* bufs[2] = {xqA, xqB};
  int layer_grid = (N + 63) / 64;
  for (int l = 0; l < 3; ++l) {
    k_layer<<<layer_grid, 256, 0, stream>>>(bufs[l & 1], row_off, epk, comp[l],
                                            bases[l], loopw[l], biasp[l],
                                            bufs[(l + 1) & 1], N);
  }

  // ---- predictor + sigmoid (reads fp16 activations)
  k_pred<<<(N + 3) / 4, 256, 0, stream>>>(bufs[1], pred_w, pred_b, (float*)d_out, N);
}

// Round 6
// 424.269 us; speedup vs baseline: 1.2857x; 1.2857x over previous
//
#include <hip/hip_runtime.h>
#include <hip/hip_bf16.h>
#include <hip/hip_fp16.h>

// RGCN: 3 layers of basis-decomposed relational graph conv + predictor.
// CSR build via 2-level counting sort (NO global atomics).
// SPLIT per layer (fusion regressed: 40KB LDS -> 33% occupancy killed the
// latency-bound gather; R5 post-mortem):
//   k_aggregate: wave/node, lane=channel, fp16 gather, 8-deep unroll
//                (8 rows = 1KB in flight per wave), fp32 accum, fp16 Z out.
//   k_gemm:      out = relu([Z | x] @ [bases ; loop_w] + bias); A-panels fp16
//                (2 k per b32 LDS read, XOR-swizzled), W fp32 in LDS;
//                emits fp16 activations only (fp16-only chain: R5-validated
//                absmax 1.17e-2 < 2e-2).
// Final: sigmoid(x @ pred_w + pred_b) from fp16.

#define NB1 196        // ceil(100000/512) coarse buckets
#define NBLK1 256      // L1 partition blocks
#define BUCKET_SHIFT 9 // 512 nodes per bucket

typedef unsigned short ushort_t;

__device__ inline ushort_t f2h(float f) {
  __half h = __float2half_rn(f);
  return *(ushort_t*)&h;
}
__device__ inline float h2f(ushort_t u) {
  __half h = *(__half*)&u;
  return __half2float(h);
}

// inclusive scan of one int per thread across a 256-thread block
__device__ inline int block_incl_scan_256(int v, int* wsums) {
  int lane = threadIdx.x & 63, wid = threadIdx.x >> 6;
  int s = v;
#pragma unroll
  for (int off = 1; off < 64; off <<= 1) {
    int u = __shfl_up(s, off, 64);
    if (lane >= off) s += u;
  }
  if (lane == 63) wsums[wid] = s;
  __syncthreads();
  if (threadIdx.x == 0) {
    int a = 0;
#pragma unroll
    for (int w = 0; w < 4; ++w) { int t = wsums[w]; wsums[w] = a; a += t; }
  }
  __syncthreads();
  return s + wsums[wid];
}

// ---- L1 pass a: per-block LDS histogram over 196 coarse buckets
__global__ void __launch_bounds__(256) k_l1hist(const int* __restrict__ dst,
                                                int* __restrict__ H, int E, int chunk) {
  __shared__ int h[NB1];
  int t = threadIdx.x;
  if (t < NB1) h[t] = 0;
  __syncthreads();
  int beg = blockIdx.x * chunk;
  int end = min(beg + chunk, E);
  for (int i = beg + t; i < end; i += 256) atomicAdd(&h[dst[i] >> BUCKET_SHIFT], 1);
  __syncthreads();
  if (t < NB1) H[blockIdx.x * NB1 + t] = h[t];
}

// ---- L1 pass b: scan each bucket's column of H -> excl offsets + totals
__global__ void __launch_bounds__(256) k_colscan(int* __restrict__ H,
                                                 int* __restrict__ total) {
  __shared__ int wsums[4];
  int b = blockIdx.x;
  int t = threadIdx.x;
  int v = H[t * NB1 + b];
  int s = block_incl_scan_256(v, wsums);
  H[t * NB1 + b] = s - v;
  if (t == 255) total[b] = s;
}

// ---- L1 pass c: scan bucket totals -> bucket_base
__global__ void __launch_bounds__(256) k_basescan(const int* __restrict__ total,
                                                  int* __restrict__ bucket_base,
                                                  int* __restrict__ row_off, int N) {
  __shared__ int wsums[4];
  int t = threadIdx.x;
  int v = (t < NB1) ? total[t] : 0;
  int s = block_incl_scan_256(v, wsums);
  if (t < NB1) bucket_base[t] = s - v;
  if (t == 255) { bucket_base[NB1] = s; row_off[N] = s; }
}

// ---- L1 pass d: scatter edges into bucket-partitioned epk1 via LDS cursors
__global__ void __launch_bounds__(256) k_scatter1(
    const int* __restrict__ src, const int* __restrict__ dst,
    const int* __restrict__ et, const int* __restrict__ H,
    const int* __restrict__ bucket_base, int* __restrict__ epk1,
    int E, int chunk) {
  __shared__ int cur[NB1];
  int t = threadIdx.x;
  if (t < NB1) cur[t] = bucket_base[t] + H[blockIdx.x * NB1 + t];
  __syncthreads();
  int beg = blockIdx.x * chunk;
  int end = min(beg + chunk, E);
  for (int i = beg + t; i < end; i += 256) {
    int d = dst[i];
    int b = d >> BUCKET_SHIFT;
    int p = atomicAdd(&cur[b], 1);
    epk1[p] = src[i] | (et[i] << 17) | ((d & 511) << 19);
  }
}

// ---- L2: per-bucket exact sort by dst_local (512 bins) -> epk + row_off
__global__ void __launch_bounds__(256) k_bucket(
    const int* __restrict__ epk1, const int* __restrict__ bucket_base,
    int* __restrict__ epk, int* __restrict__ row_off, int N) {
  __shared__ int hist[512];
  __shared__ int cur[512];
  __shared__ int wsums[4];
  int b = blockIdx.x;
  int t = threadIdx.x;
  int ebase = bucket_base[b], eend = bucket_base[b + 1];
  hist[t] = 0; hist[t + 256] = 0;
  __syncthreads();
  for (int i = ebase + t; i < eend; i += 256) atomicAdd(&hist[epk1[i] >> 19], 1);
  __syncthreads();
  int h0 = hist[2 * t], h1 = hist[2 * t + 1];
  int pair = h0 + h1;
  int incl = block_incl_scan_256(pair, wsums);
  int e0 = incl - pair;
  cur[2 * t] = ebase + e0;
  cur[2 * t + 1] = ebase + e0 + h0;
  int n0 = (b << BUCKET_SHIFT) + 2 * t;
  if (n0 < N) row_off[n0] = ebase + e0;
  if (n0 + 1 < N) row_off[n0 + 1] = ebase + e0 + h0;
  __syncthreads();
  for (int i = ebase + t; i < eend; i += 256) {
    int pk = epk1[i];
    int p = atomicAdd(&cur[pk >> 19], 1);
    epk[p] = pk;
  }
}

// ---- quantize fp32 -> fp16 (RTNE), vectorized
__global__ void __launch_bounds__(256) k_quant(const float* __restrict__ in,
                                               ushort_t* __restrict__ out, int n4) {
  int i = blockIdx.x * blockDim.x + threadIdx.x;
  if (i < n4) {
    float4 v = ((const float4*)in)[i];
    ushort4 q;
    q.x = f2h(v.x); q.y = f2h(v.y);
    q.z = f2h(v.z); q.w = f2h(v.w);
    ((ushort4*)out)[i] = q;
  }
}

// One wave per node; lane = channel. fp16 gather (128B/edge row), 8-deep
// unroll: 8 rows (1KB) in flight per wave; epk loads vectorize to dwordx4.
// Emits Z as fp16: Zh[node][0..63]=basis0, [64..127]=basis1.
__global__ void __launch_bounds__(256) k_aggregate(
    const ushort_t* __restrict__ xq, const int* __restrict__ row_off,
    const int* __restrict__ epk, const float* __restrict__ comp,
    ushort_t* __restrict__ Zh, int N) {
  __shared__ float s_comp[8];
  if (threadIdx.x < 8) s_comp[threadIdx.x] = comp[threadIdx.x];
  __syncthreads();
  int node = blockIdx.x * 4 + (threadIdx.x >> 6);
  int lane = threadIdx.x & 63;
  if (node >= N) return;
  int beg = row_off[node], end = row_off[node + 1];
  float z0 = 0.f, z1 = 0.f;
  int e = beg;
  for (; e + 7 < end; e += 8) {
    int pk[8];
    float xv[8];
#pragma unroll
    for (int u = 0; u < 8; ++u) pk[u] = epk[e + u];
#pragma unroll
    for (int u = 0; u < 8; ++u)
      xv[u] = h2f(xq[(size_t)(pk[u] & 0x1FFFF) * 64 + lane]);
#pragma unroll
    for (int u = 0; u < 8; ++u) {
      int r = (pk[u] >> 17) & 3;
      z0 = fmaf(s_comp[r * 2 + 0], xv[u], z0);
      z1 = fmaf(s_comp[r * 2 + 1], xv[u], z1);
    }
  }
  for (; e < end; ++e) {
    int pk = epk[e];
    int s = pk & 0x1FFFF, r = (pk >> 17) & 3;
    float xv = h2f(xq[(size_t)s * 64 + lane]);
    z0 = fmaf(s_comp[r * 2 + 0], xv, z0);
    z1 = fmaf(s_comp[r * 2 + 1], xv, z1);
  }
  Zh[(size_t)node * 128 + lane] = f2h(z0);
  Zh[(size_t)node * 128 + 64 + lane] = f2h(z1);
}

// out = relu([Z | x] @ [bases ; loop_w] + bias), A fp16 (2 k per b32 LDS
// read, XOR-swizzled), W fp32 in LDS. Emits fp16 activations only.
// 64-row x 64-col tile per block, 256 threads, 4-row x 4-col micro-tile.
__global__ void __launch_bounds__(256) k_gemm(
    const ushort_t* __restrict__ Zh, const ushort_t* __restrict__ xq,
    const float* __restrict__ bases, const float* __restrict__ loopw,
    const float* __restrict__ bias, ushort_t* __restrict__ xqOut, int N) {
  __shared__ float sW[64 * 64];        // 16 KB: fp32 W chunk
  __shared__ unsigned int sA[64 * 32]; // 8 KB: fp16-pair A panel (swizzled)
  int t = threadIdx.x;
  int tx = t & 15, ty = t >> 4;
  int row0 = blockIdx.x * 64;
  float acc[4][4] = {{0.f, 0.f, 0.f, 0.f}};

#pragma unroll 1
  for (int ch = 0; ch < 3; ++ch) {
    __syncthreads();  // protect previous chunk's sW/sA reads
    // ---- stage W chunk (rows ch*64.. of stacked 192x64 W)
    const float4* wsrc = (ch < 2) ? ((const float4*)bases + (size_t)ch * 1024)
                                  : (const float4*)loopw;
#pragma unroll
    for (int q = 0; q < 4; ++q) ((float4*)sW)[t + q * 256] = wsrc[t + q * 256];
    // ---- stage A panel: 64 rows x 32 u32 (fp16 pairs), XOR-swizzled
    {
      int r = t >> 2;           // row 0..63
      int co = (t & 3) * 8;     // u32 offset within row: 0,8,16,24
      int grow = row0 + r;
      uint4 v0 = make_uint4(0, 0, 0, 0), v1 = v0;
      if (grow < N) {
        const uint4* p;
        if (ch == 0)      p = (const uint4*)(Zh + (size_t)grow * 128) + (t & 3) * 2;
        else if (ch == 1) p = (const uint4*)(Zh + (size_t)grow * 128 + 64) + (t & 3) * 2;
        else              p = (const uint4*)(xq + (size_t)grow * 64) + (t & 3) * 2;
        v0 = p[0]; v1 = p[1];
      }
      int sw = r & 31;
      unsigned int* a = (unsigned int*)&v0;
      unsigned int* b = (unsigned int*)&v1;
#pragma unroll
      for (int p2 = 0; p2 < 4; ++p2) {
        sA[r * 32 + ((co + p2) ^ sw)]     = a[p2];
        sA[r * 32 + ((co + 4 + p2) ^ sw)] = b[p2];
      }
    }
    __syncthreads();
    // ---- compute: m indexes k-pairs (2 k per iteration)
#pragma unroll 4
    for (int m = 0; m < 32; ++m) {
      float4 w0 = *(const float4*)(sW + (2 * m) * 64 + tx * 4);
      float4 w1 = *(const float4*)(sW + (2 * m + 1) * 64 + tx * 4);
#pragma unroll
      for (int j = 0; j < 4; ++j) {
        int rj = ty * 4 + j;
        unsigned int pr = sA[rj * 32 + (m ^ (rj & 31))];
        float a0 = h2f((ushort_t)(pr & 0xffff));
        float a1 = h2f((ushort_t)(pr >> 16));
        acc[j][0] = fmaf(a0, w0.x, acc[j][0]);
        acc[j][1] = fmaf(a0, w0.y, acc[j][1]);
        acc[j][2] = fmaf(a0, w0.z, acc[j][2]);
        acc[j][3] = fmaf(a0, w0.w, acc[j][3]);
        acc[j][0] = fmaf(a1, w1.x, acc[j][0]);
        acc[j][1] = fmaf(a1, w1.y, acc[j][1]);
        acc[j][2] = fmaf(a1, w1.z, acc[j][2]);
        acc[j][3] = fmaf(a1, w1.w, acc[j][3]);
      }
    }
  }
  // ---- epilogue: bias + relu -> fp16 activations
  float4 bv = *(const float4*)(bias + tx * 4);
#pragma unroll
  for (int j = 0; j < 4; ++j) {
    int r = row0 + ty * 4 + j;
    if (r < N) {
      ushort4 qv;
      qv.x = f2h(fmaxf(acc[j][0] + bv.x, 0.f));
      qv.y = f2h(fmaxf(acc[j][1] + bv.y, 0.f));
      qv.z = f2h(fmaxf(acc[j][2] + bv.z, 0.f));
      qv.w = f2h(fmaxf(acc[j][3] + bv.w, 0.f));
      *(ushort4*)(xqOut + (size_t)r * 64 + tx * 4) = qv;
    }
  }
}

__global__ void __launch_bounds__(256) k_pred(
    const ushort_t* __restrict__ x, const float* __restrict__ pw,
    const float* __restrict__ pb, float* __restrict__ out, int N) {
  int node = blockIdx.x * 4 + (threadIdx.x >> 6);
  int lane = threadIdx.x & 63;
  if (node >= N) return;
  float v = h2f(x[(size_t)node * 64 + lane]) * pw[lane];
#pragma unroll
  for (int off = 32; off > 0; off >>= 1) v += __shfl_down(v, off, 64);
  if (lane == 0) {
    float logit = v + pb[0];
    out[node] = 1.f / (1.f + expf(-logit));
  }
}

extern "C" void kernel_launch(void* const* d_in, const int* in_sizes, int n_in,
                              void* d_out, int out_size, void* d_ws, size_t ws_size,
                              hipStream_t stream) {
  const float* features = (const float*)d_in[0];
  const int* src = (const int*)d_in[1];
  const int* dst = (const int*)d_in[2];
  const int* et  = (const int*)d_in[3];
  const float* bases[3] = {(const float*)d_in[4], (const float*)d_in[8],  (const float*)d_in[12]};
  const float* comp[3]  = {(const float*)d_in[5], (const float*)d_in[9],  (const float*)d_in[13]};
  const float* loopw[3] = {(const float*)d_in[6], (const float*)d_in[10], (const float*)d_in[14]};
  const float* biasp[3] = {(const float*)d_in[7], (const float*)d_in[11], (const float*)d_in[15]};
  const float* pred_w = (const float*)d_in[16];
  const float* pred_b = (const float*)d_in[17];

  const int N = in_sizes[0] / 64;   // 100000
  const int E = in_sizes[1];        // 1600000

  char* ws = (char*)d_ws;
  size_t off = 0;
  auto take = [&](size_t bytes) {
    char* p = ws + off;
    off += (bytes + 255) & ~(size_t)255;
    return p;
  };
  int*      row_off     = (int*)     take((size_t)(N + 1) * 4);
  int*      H           = (int*)     take((size_t)NBLK1 * NB1 * 4);
  int*      total       = (int*)     take((size_t)NB1 * 4);
  int*      bucket_base = (int*)     take((size_t)(NB1 + 1) * 4);
  int*      epk         = (int*)     take((size_t)(E + 8) * 4);  // +pad
  ushort_t* Zh          = (ushort_t*)take((size_t)N * 128 * 2);
  ushort_t* xqA         = (ushort_t*)take((size_t)N * 64 * 2);
  ushort_t* xqB         = (ushort_t*)take((size_t)N * 64 * 2);
  int*      epk1        = (int*)Zh;   // alias: Zh dead during CSR build
  (void)ws_size;

  // ---- CSR build: 2-level counting sort, no global atomics
  int chunk = (E + NBLK1 - 1) / NBLK1;
  k_l1hist  <<<NBLK1, 256, 0, stream>>>(dst, H, E, chunk);
  k_colscan <<<NB1,   256, 0, stream>>>(H, total);
  k_basescan<<<1,     256, 0, stream>>>(total, bucket_base, row_off, N);
  k_scatter1<<<NBLK1, 256, 0, stream>>>(src, dst, et, H, bucket_base, epk1, E, chunk);
  k_bucket  <<<NB1,   256, 0, stream>>>(epk1, bucket_base, epk, row_off, N);

  // ---- quantize input features to fp16
  k_quant<<<(N * 16 + 255) / 256, 256, 0, stream>>>(features, xqA, N * 16);

  // ---- 3 RGCN layers (fp16 activations ping-pong)
  ushort_t* bufs[2] = {xqA, xqB};
  int agg_grid = (N + 3) / 4;
  int gemm_grid = (N + 63) / 64;
  for (int l = 0; l < 3; ++l) {
    k_aggregate<<<agg_grid, 256, 0, stream>>>(bufs[l & 1], row_off, epk,
                                              comp[l], Zh, N);
    k_gemm<<<gemm_grid, 256, 0, stream>>>(Zh, bufs[l & 1], bases[l], loopw[l],
                                          biasp[l], bufs[(l + 1) & 1], N);
  }

  // ---- predictor + sigmoid (reads fp16 activations)
  k_pred<<<(N + 3) / 4, 256, 0, stream>>>(bufs[1], pred_w, pred_b, (float*)d_out, N);
}

// Round 7
// 350.446 us; speedup vs baseline: 1.5566x; 1.2107x over previous
//
#include <hip/hip_runtime.h>
#include <hip/hip_bf16.h>
#include <hip/hip_fp16.h>

// RGCN: 3 layers of basis-decomposed relational graph conv + predictor.
// CSR build via 2-level counting sort (NO global atomics).
// k_aggregate: wave/node fp16 gather (structural limit ~68us: per-CU
//   outstanding-line cap saturated; R6 unroll null-result).
// k_gemm_mfma: out = relu([Z|x] @ [bases;loop_w] + bias) via
//   mfma_f32_16x16x32_f16. A-frags straight from global (rows read once);
//   W^T fp16 in LDS with SPLIT RESIDUAL (W = Wh + Wr, 2 chained MFMAs) so
//   weight fp16-quantization error cancels to ~2^-22. Emits fp16 acts.
// Final: sigmoid(x @ pred_w + pred_b) from fp16.

#define NB1 196        // ceil(100000/512) coarse buckets
#define NBLK1 256      // L1 partition blocks
#define BUCKET_SHIFT 9 // 512 nodes per bucket
#define WT_LD 200      // padded k-stride (fp16) for W^T LDS: 400B = 2-way free

typedef unsigned short ushort_t;
typedef _Float16 h8 __attribute__((ext_vector_type(8)));
typedef float f32x4 __attribute__((ext_vector_type(4)));

__device__ inline ushort_t f2h(float f) {
  __half h = __float2half_rn(f);
  return *(ushort_t*)&h;
}
__device__ inline float h2f(ushort_t u) {
  __half h = *(__half*)&u;
  return __half2float(h);
}

// inclusive scan of one int per thread across a 256-thread block
__device__ inline int block_incl_scan_256(int v, int* wsums) {
  int lane = threadIdx.x & 63, wid = threadIdx.x >> 6;
  int s = v;
#pragma unroll
  for (int off = 1; off < 64; off <<= 1) {
    int u = __shfl_up(s, off, 64);
    if (lane >= off) s += u;
  }
  if (lane == 63) wsums[wid] = s;
  __syncthreads();
  if (threadIdx.x == 0) {
    int a = 0;
#pragma unroll
    for (int w = 0; w < 4; ++w) { int t = wsums[w]; wsums[w] = a; a += t; }
  }
  __syncthreads();
  return s + wsums[wid];
}

// ---- L1 pass a: per-block LDS histogram over 196 coarse buckets
__global__ void __launch_bounds__(256) k_l1hist(const int* __restrict__ dst,
                                                int* __restrict__ H, int E, int chunk) {
  __shared__ int h[NB1];
  int t = threadIdx.x;
  if (t < NB1) h[t] = 0;
  __syncthreads();
  int beg = blockIdx.x * chunk;
  int end = min(beg + chunk, E);
  for (int i = beg + t; i < end; i += 256) atomicAdd(&h[dst[i] >> BUCKET_SHIFT], 1);
  __syncthreads();
  if (t < NB1) H[blockIdx.x * NB1 + t] = h[t];
}

// ---- L1 pass b: scan each bucket's column of H -> excl offsets + totals
__global__ void __launch_bounds__(256) k_colscan(int* __restrict__ H,
                                                 int* __restrict__ total) {
  __shared__ int wsums[4];
  int b = blockIdx.x;
  int t = threadIdx.x;
  int v = H[t * NB1 + b];
  int s = block_incl_scan_256(v, wsums);
  H[t * NB1 + b] = s - v;
  if (t == 255) total[b] = s;
}

// ---- L1 pass c: scan bucket totals -> bucket_base
__global__ void __launch_bounds__(256) k_basescan(const int* __restrict__ total,
                                                  int* __restrict__ bucket_base,
                                                  int* __restrict__ row_off, int N) {
  __shared__ int wsums[4];
  int t = threadIdx.x;
  int v = (t < NB1) ? total[t] : 0;
  int s = block_incl_scan_256(v, wsums);
  if (t < NB1) bucket_base[t] = s - v;
  if (t == 255) { bucket_base[NB1] = s; row_off[N] = s; }
}

// ---- L1 pass d: scatter edges into bucket-partitioned epk1 via LDS cursors
__global__ void __launch_bounds__(256) k_scatter1(
    const int* __restrict__ src, const int* __restrict__ dst,
    const int* __restrict__ et, const int* __restrict__ H,
    const int* __restrict__ bucket_base, int* __restrict__ epk1,
    int E, int chunk) {
  __shared__ int cur[NB1];
  int t = threadIdx.x;
  if (t < NB1) cur[t] = bucket_base[t] + H[blockIdx.x * NB1 + t];
  __syncthreads();
  int beg = blockIdx.x * chunk;
  int end = min(beg + chunk, E);
  for (int i = beg + t; i < end; i += 256) {
    int d = dst[i];
    int b = d >> BUCKET_SHIFT;
    int p = atomicAdd(&cur[b], 1);
    epk1[p] = src[i] | (et[i] << 17) | ((d & 511) << 19);
  }
}

// ---- L2: per-bucket exact sort by dst_local (512 bins) -> epk + row_off
__global__ void __launch_bounds__(256) k_bucket(
    const int* __restrict__ epk1, const int* __restrict__ bucket_base,
    int* __restrict__ epk, int* __restrict__ row_off, int N) {
  __shared__ int hist[512];
  __shared__ int cur[512];
  __shared__ int wsums[4];
  int b = blockIdx.x;
  int t = threadIdx.x;
  int ebase = bucket_base[b], eend = bucket_base[b + 1];
  hist[t] = 0; hist[t + 256] = 0;
  __syncthreads();
  for (int i = ebase + t; i < eend; i += 256) atomicAdd(&hist[epk1[i] >> 19], 1);
  __syncthreads();
  int h0 = hist[2 * t], h1 = hist[2 * t + 1];
  int pair = h0 + h1;
  int incl = block_incl_scan_256(pair, wsums);
  int e0 = incl - pair;
  cur[2 * t] = ebase + e0;
  cur[2 * t + 1] = ebase + e0 + h0;
  int n0 = (b << BUCKET_SHIFT) + 2 * t;
  if (n0 < N) row_off[n0] = ebase + e0;
  if (n0 + 1 < N) row_off[n0 + 1] = ebase + e0 + h0;
  __syncthreads();
  for (int i = ebase + t; i < eend; i += 256) {
    int pk = epk1[i];
    int p = atomicAdd(&cur[pk >> 19], 1);
    epk[p] = pk;
  }
}

// ---- quantize fp32 -> fp16 (RTNE), vectorized
__global__ void __launch_bounds__(256) k_quant(const float* __restrict__ in,
                                               ushort_t* __restrict__ out, int n4) {
  int i = blockIdx.x * blockDim.x + threadIdx.x;
  if (i < n4) {
    float4 v = ((const float4*)in)[i];
    ushort4 q;
    q.x = f2h(v.x); q.y = f2h(v.y);
    q.z = f2h(v.z); q.w = f2h(v.w);
    ((ushort4*)out)[i] = q;
  }
}

// One wave per node; lane = channel. fp16 gather (128B/edge row), 8-deep
// unroll. Emits Z as fp16: Zh[node][0..63]=basis0, [64..127]=basis1.
__global__ void __launch_bounds__(256) k_aggregate(
    const ushort_t* __restrict__ xq, const int* __restrict__ row_off,
    const int* __restrict__ epk, const float* __restrict__ comp,
    ushort_t* __restrict__ Zh, int N) {
  __shared__ float s_comp[8];
  if (threadIdx.x < 8) s_comp[threadIdx.x] = comp[threadIdx.x];
  __syncthreads();
  int node = blockIdx.x * 4 + (threadIdx.x >> 6);
  int lane = threadIdx.x & 63;
  if (node >= N) return;
  int beg = row_off[node], end = row_off[node + 1];
  float z0 = 0.f, z1 = 0.f;
  int e = beg;
  for (; e + 7 < end; e += 8) {
    int pk[8];
    float xv[8];
#pragma unroll
    for (int u = 0; u < 8; ++u) pk[u] = epk[e + u];
#pragma unroll
    for (int u = 0; u < 8; ++u)
      xv[u] = h2f(xq[(size_t)(pk[u] & 0x1FFFF) * 64 + lane]);
#pragma unroll
    for (int u = 0; u < 8; ++u) {
      int r = (pk[u] >> 17) & 3;
      z0 = fmaf(s_comp[r * 2 + 0], xv[u], z0);
      z1 = fmaf(s_comp[r * 2 + 1], xv[u], z1);
    }
  }
  for (; e < end; ++e) {
    int pk = epk[e];
    int s = pk & 0x1FFFF, r = (pk >> 17) & 3;
    float xv = h2f(xq[(size_t)s * 64 + lane]);
    z0 = fmaf(s_comp[r * 2 + 0], xv, z0);
    z1 = fmaf(s_comp[r * 2 + 1], xv, z1);
  }
  Zh[(size_t)node * 128 + lane] = f2h(z0);
  Zh[(size_t)node * 128 + 64 + lane] = f2h(z1);
}

// ---- MFMA GEMM: out = relu([Z | x](64x192 fp16) @ W(192x64) + bias)
// A-frags from global (each row read once); W^T fp16 + residual in LDS.
// Layouts (mfma_f32_16x16x32_f16): A row=l&15, k=8*(l>>4)+j;
// B k=8*(l>>4)+j, col=l&15; C/D col=l&15, row=4*(l>>4)+reg.
__global__ void __launch_bounds__(256) k_gemm_mfma(
    const ushort_t* __restrict__ Zh, const ushort_t* __restrict__ xq,
    const float* __restrict__ bases, const float* __restrict__ loopw,
    const float* __restrict__ bias, ushort_t* __restrict__ xqOut, int N) {
  __shared__ ushort_t sWh[64 * WT_LD];  // W^T fp16:      25.6 KB
  __shared__ ushort_t sWr[64 * WT_LD];  // W^T residual:  25.6 KB
  int t = threadIdx.x;
  int w = t >> 6, l = t & 63;
  int lr = l & 15, lg = l >> 4;
  int row0 = blockIdx.x * 64 + w * 16;

  // ---- issue A-frag global loads FIRST (independent of LDS staging)
  int arow = row0 + lr;
  bool rok = arow < N;
  h8 a[6];
#pragma unroll
  for (int kb = 0; kb < 6; ++kb) {
    int k0 = kb * 32 + lg * 8;
    uint4 u = make_uint4(0, 0, 0, 0);
    if (rok) {
      if (kb < 4) u = *(const uint4*)(Zh + (size_t)arow * 128 + k0);
      else        u = *(const uint4*)(xq + (size_t)arow * 64 + (k0 - 128));
    }
    a[kb] = *(h8*)&u;
  }

  // ---- stage W^T as fp16 + residual (W = Wh + Wr exactly to ~2^-22)
#pragma unroll 4
  for (int i = 0; i < 48; ++i) {
    int idx = i * 256 + t;        // 0..12287
    int k = idx >> 6, c = idx & 63;
    float wv = (k < 128) ? bases[idx] : loopw[idx - 8192];
    ushort_t hh = f2h(wv);
    sWh[c * WT_LD + k] = hh;
    sWr[c * WT_LD + k] = f2h(wv - h2f(hh));
  }
  __syncthreads();

  // ---- MFMA: 4 col-tiles x 6 k-steps x (Wh + Wr)
  f32x4 acc[4];
#pragma unroll
  for (int c = 0; c < 4; ++c) acc[c] = (f32x4){0.f, 0.f, 0.f, 0.f};
#pragma unroll
  for (int c = 0; c < 4; ++c) {
    int col = c * 16 + lr;
    const ushort_t* bh = sWh + col * WT_LD + lg * 8;
    const ushort_t* br = sWr + col * WT_LD + lg * 8;
#pragma unroll
    for (int kb = 0; kb < 6; ++kb) {
      h8 vb = *(const h8*)(bh + kb * 32);
      acc[c] = __builtin_amdgcn_mfma_f32_16x16x32_f16(a[kb], vb, acc[c], 0, 0, 0);
      h8 vr = *(const h8*)(br + kb * 32);
      acc[c] = __builtin_amdgcn_mfma_f32_16x16x32_f16(a[kb], vr, acc[c], 0, 0, 0);
    }
  }

  // ---- epilogue: bias + relu -> fp16 activations
#pragma unroll
  for (int c = 0; c < 4; ++c) {
    int col = c * 16 + lr;
    float bv = bias[col];
#pragma unroll
    for (int r = 0; r < 4; ++r) {
      int grow = row0 + lg * 4 + r;
      if (grow < N)
        xqOut[(size_t)grow * 64 + col] = f2h(fmaxf(acc[c][r] + bv, 0.f));
    }
  }
}

__global__ void __launch_bounds__(256) k_pred(
    const ushort_t* __restrict__ x, const float* __restrict__ pw,
    const float* __restrict__ pb, float* __restrict__ out, int N) {
  int node = blockIdx.x * 4 + (threadIdx.x >> 6);
  int lane = threadIdx.x & 63;
  if (node >= N) return;
  float v = h2f(x[(size_t)node * 64 + lane]) * pw[lane];
#pragma unroll
  for (int off = 32; off > 0; off >>= 1) v += __shfl_down(v, off, 64);
  if (lane == 0) {
    float logit = v + pb[0];
    out[node] = 1.f / (1.f + expf(-logit));
  }
}

extern "C" void kernel_launch(void* const* d_in, const int* in_sizes, int n_in,
                              void* d_out, int out_size, void* d_ws, size_t ws_size,
                              hipStream_t stream) {
  const float* features = (const float*)d_in[0];
  const int* src = (const int*)d_in[1];
  const int* dst = (const int*)d_in[2];
  const int* et  = (const int*)d_in[3];
  const float* bases[3] = {(const float*)d_in[4], (const float*)d_in[8],  (const float*)d_in[12]};
  const float* comp[3]  = {(const float*)d_in[5], (const float*)d_in[9],  (const float*)d_in[13]};
  const float* loopw[3] = {(const float*)d_in[6], (const float*)d_in[10], (const float*)d_in[14]};
  const float* biasp[3] = {(const float*)d_in[7], (const float*)d_in[11], (const float*)d_in[15]};
  const float* pred_w = (const float*)d_in[16];
  const float* pred_b = (const float*)d_in[17];

  const int N = in_sizes[0] / 64;   // 100000
  const int E = in_sizes[1];        // 1600000

  char* ws = (char*)d_ws;
  size_t off = 0;
  auto take = [&](size_t bytes) {
    char* p = ws + off;
    off += (bytes + 255) & ~(size_t)255;
    return p;
  };
  int*      row_off     = (int*)     take((size_t)(N + 1) * 4);
  int*      H           = (int*)     take((size_t)NBLK1 * NB1 * 4);
  int*      total       = (int*)     take((size_t)NB1 * 4);
  int*      bucket_base = (int*)     take((size_t)(NB1 + 1) * 4);
  int*      epk         = (int*)     take((size_t)(E + 8) * 4);  // +pad
  ushort_t* Zh          = (ushort_t*)take((size_t)N * 128 * 2);
  ushort_t* xqA         = (ushort_t*)take((size_t)N * 64 * 2);
  ushort_t* xqB         = (ushort_t*)take((size_t)N * 64 * 2);
  int*      epk1        = (int*)Zh;   // alias: Zh dead during CSR build
  (void)ws_size;

  // ---- CSR build: 2-level counting sort, no global atomics
  int chunk = (E + NBLK1 - 1) / NBLK1;
  k_l1hist  <<<NBLK1, 256, 0, stream>>>(dst, H, E, chunk);
  k_colscan <<<NB1,   256, 0, stream>>>(H, total);
  k_basescan<<<1,     256, 0, stream>>>(total, bucket_base, row_off, N);
  k_scatter1<<<NBLK1, 256, 0, stream>>>(src, dst, et, H, bucket_base, epk1, E, chunk);
  k_bucket  <<<NB1,   256, 0, stream>>>(epk1, bucket_base, epk, row_off, N);

  // ---- quantize input features to fp16
  k_quant<<<(N * 16 + 255) / 256, 256, 0, stream>>>(features, xqA, N * 16);

  // ---- 3 RGCN layers (fp16 activations ping-pong)
  ushort_t* bufs[2] = {xqA, xqB};
  int agg_grid = (N + 3) / 4;
  int gemm_grid = (N + 63) / 64;
  for (int l = 0; l < 3; ++l) {
    k_aggregate<<<agg_grid, 256, 0, stream>>>(bufs[l & 1], row_off, epk,
                                              comp[l], Zh, N);
    k_gemm_mfma<<<gemm_grid, 256, 0, stream>>>(Zh, bufs[l & 1], bases[l],
                                               loopw[l], biasp[l],
                                               bufs[(l + 1) & 1], N);
  }

  // ---- predictor + sigmoid (reads fp16 activations)
  k_pred<<<(N + 3) / 4, 256, 0, stream>>>(bufs[1], pred_w, pred_b, (float*)d_out, N);
}